// Round 5
// baseline (553.409 us; speedup 1.0000x reference)
//
#include <hip/hip_runtime.h>

// LSTM anomaly detector: B=4096, T=512, I=3, H=64 (4H=256 gates)
// R5: 8-row blocks, grid=512 -> 2 blocks/CU (2 waves/SIMD). MFMA blocks its
// wave, so overlap must come from a sibling block's waves (m114 co-schedule).
// Preacts round-trip through LDS so activations are fully lane-packed
// (2 h-elems/lane, 20 trans/lane/step instead of 40). Activation input
// scales folded into weights. h exchange single-buffered (2 barriers/step).

#define TLEN 512
#define TCHUNK 64
#define NCHUNK 8

typedef float  float4_t __attribute__((ext_vector_type(4)));
typedef float  float2_t __attribute__((ext_vector_type(2)));
typedef __bf16 bf16x8   __attribute__((ext_vector_type(8)));

__device__ __forceinline__ float fexp2(float x){ return __builtin_amdgcn_exp2f(x); }
__device__ __forceinline__ float frcp (float x){ return __builtin_amdgcn_rcpf(x); }

// setup-only: scale then RNE hi/lo split (~2^-17 rel err)
__device__ __forceinline__ void split8s(const float* v, float s, bf16x8& hi, bf16x8& lo){
  #pragma unroll
  for (int j = 0; j < 8; j++){
    const float xx = v[j]*s;
    __bf16 h = (__bf16)xx;
    hi[j] = h;
    lo[j] = (__bf16)(xx - (float)h);
  }
}

#define MFMA(a,b,c) __builtin_amdgcn_mfma_f32_16x16x32_bf16((a),(b),(c),0,0,0)

// P (preact) layout: [tl 4][gc 64][m 16 + pad 4] -> stride 20 (16B-aligned b128)
#define PSTR 20
#define PTL  1280

__global__ __launch_bounds__(256, 2)
void LSTMAnomalyDetector_kernel(
    const float* __restrict__ x,     const float* __restrict__ W_ih,
    const float* __restrict__ W_hh,  const float* __restrict__ b_ih,
    const float* __restrict__ b_hh,  const float* __restrict__ W_dec,
    const float* __restrict__ b_dec, float* __restrict__ out)
{
  __shared__ __align__(16) unsigned short HS[2304];  // HHI @0, HLO @1152 : [16 rows][72]
  __shared__ __align__(16) float LPP[4*PTL];         // preacts, 20.5 KB
  __shared__ __align__(16) float XOF[1568];          // [8][196] fp32 x staging
  __shared__ __align__(16) float XP4[4096];          // [2 parity][64 t][8 row][4]
  __shared__ __align__(16) float OOF[1568];          // [8][196] out staging

  const int tid  = threadIdx.x;
  const int w    = tid >> 6;
  const int lane = tid & 63;
  const int q    = lane >> 4;
  const int lid  = lane & 15;
  const int b0   = blockIdx.x * 8;     // batch rows [b0, b0+8)
  const int cw   = w*16 + lid;         // this lane's H/gate column
  const int m4   = (q & 1) * 4;        // xg seed row base (rows 0-7 for all q)

  // ---- resident weights (activation scales folded: i,f,o -> -1/ln2·? ; g -> +2/ln2) ----
  const float sc[4] = {-1.44269504f, -1.44269504f, 2.88539008f, -1.44269504f};
  bf16x8 Bh[4][2], Bl[4][2];
  bf16x8 Dh[2],    Dl[2];
  float  Wi0[4], Wi1[4], Wi2[4], bia[4];

  #pragma unroll
  for (int tl = 0; tl < 4; tl++){
    const int g = tl*64 + cw;
    #pragma unroll
    for (int kt = 0; kt < 2; kt++){
      const float* p = W_hh + g*64 + kt*32 + q*8;
      float v[8];
      #pragma unroll
      for (int j = 0; j < 8; j++) v[j] = p[j];
      split8s(v, sc[tl], Bh[tl][kt], Bl[tl][kt]);
    }
    Wi0[tl] = W_ih[g*3+0]*sc[tl];
    Wi1[tl] = W_ih[g*3+1]*sc[tl];
    Wi2[tl] = W_ih[g*3+2]*sc[tl];
    bia[tl] = (b_ih[g] + b_hh[g])*sc[tl];
  }
  #pragma unroll
  for (int kt = 0; kt < 2; kt++){
    float v[8] = {0.f,0.f,0.f,0.f,0.f,0.f,0.f,0.f};
    if (lid < 3){
      const float* p = W_dec + lid*64 + kt*32 + q*8;
      #pragma unroll
      for (int j = 0; j < 8; j++) v[j] = p[j];
    }
    split8s(v, 1.0f, Dh[kt], Dl[kt]);
  }
  const float bdec = (lid < 3) ? b_dec[lid] : 0.f;

  // ---- zero h LDS (h_{-1}=0; rows 8-15 stay zero forever) ----
  { unsigned int* hz = (unsigned int*)HS;
    for (int i = tid; i < 1152; i += 256) hz[i] = 0u; }

  // ---- load + pack x chunk 0 (parity 0) ----
  #pragma unroll
  for (int s = 0; s < 2; s++){
    const int f = tid + 256*s;
    if (f < 384){ const int row = f/48, off = (f%48)*4;
      *(float4_t*)&XOF[row*196+off] = *(const float4_t*)(x + (size_t)(b0+row)*1536 + off); }
  }
  __syncthreads();
  #pragma unroll
  for (int s = 0; s < 2; s++){
    const int p = tid + 256*s; const int tt = p>>3, row = p&7;
    const float* xp = &XOF[row*196 + tt*3];
    float4_t v = {xp[0], xp[1], xp[2], 0.f};
    *(float4_t*)&XP4[p*4] = v;
  }
  __syncthreads();

  // ---- state ----
  float creg[2] = {0.f, 0.f};          // c for (rows 2q+e, col cw)
  float4_t xg[4];
  #pragma unroll
  for (int r = 0; r < 4; r++){
    const float4_t xv = *(const float4_t*)&XP4[(m4+r)*4];
    #pragma unroll
    for (int tl = 0; tl < 4; tl++)
      xg[tl][r] = __builtin_fmaf(xv[0], Wi0[tl],
                  __builtin_fmaf(xv[1], Wi1[tl],
                  __builtin_fmaf(xv[2], Wi2[tl], bia[tl])));
  }
  bf16x8 ah[2], al[2];

  for (int t = 0; t < TLEN; ++t){
    const int dt = t & (TCHUNK-1);

    // ph0: rebuild h(t-1) A-frags (4 raw ds_read_b128; rows 8-15 are zeros)
    { const unsigned short* ph = &HS[lid*72 + q*8];
      ah[0] = *(const bf16x8*)&ph[0];  ah[1] = *(const bf16x8*)&ph[32];
      const unsigned short* pl = &HS[1152 + lid*72 + q*8];
      al[0] = *(const bf16x8*)&pl[0];  al[1] = *(const bf16x8*)&pl[32]; }

    // decode out(t-1) on rotating wave (uses fresh h(t-1) frags)
    if (t > 0 && w == (t & 3)){
      float4_t d = {bdec, bdec, bdec, bdec};
      d = MFMA(ah[0], Dh[0], d);
      d = MFMA(ah[1], Dh[1], d);
      d = MFMA(al[0], Dh[0], d);
      d = MFMA(al[1], Dh[1], d);
      d = MFMA(ah[0], Dl[0], d);
      d = MFMA(ah[1], Dl[1], d);
      if (lid < 3 && q < 2){
        const int dtp = (t-1) & (TCHUNK-1);
        #pragma unroll
        for (int r = 0; r < 4; r++) OOF[(q*4+r)*196 + dtp*3 + lid] = d[r];
      }
    }

    // chunk top: flush previous out-chunk, prefetch + pack next x chunk
    if (dt == 0){
      const int c = t >> 6;
      __syncthreads();
      if (c > 0){
        #pragma unroll
        for (int s = 0; s < 2; s++){
          const int f = tid + 256*s;
          if (f < 384){ const int row = f/48, off = (f%48)*4;
            *(float4_t*)(out + (size_t)(b0+row)*1536 + (c-1)*192 + off)
                = *(const float4_t*)&OOF[row*196+off]; }
        }
      }
      if (c+1 < NCHUNK){
        #pragma unroll
        for (int s = 0; s < 2; s++){
          const int f = tid + 256*s;
          if (f < 384){ const int row = f/48, off = (f%48)*4;
            *(float4_t*)&XOF[row*196+off]
                = *(const float4_t*)(x + (size_t)(b0+row)*1536 + (c+1)*192 + off); }
        }
      }
      __syncthreads();
      if (c+1 < NCHUNK){
        const int pb = ((c+1) & 1) * 2048;
        #pragma unroll
        for (int s = 0; s < 2; s++){
          const int p = tid + 256*s; const int tt = p>>3, row = p&7;
          const float* xp = &XOF[row*196 + tt*3];
          float4_t v = {xp[0], xp[1], xp[2], 0.f};
          *(float4_t*)&XP4[pb + p*4] = v;
        }
      }
    }

    // ph1: gate MFMAs (C seeded with xg) -> write preacts to LDS
    float4_t g4[4];
    #pragma unroll
    for (int tl = 0; tl < 4; tl++){
      float4_t a = xg[tl];
      a = MFMA(ah[0], Bh[tl][0], a);
      a = MFMA(ah[1], Bh[tl][1], a);
      a = MFMA(al[0], Bh[tl][0], a);
      a = MFMA(al[1], Bh[tl][1], a);
      a = MFMA(ah[0], Bl[tl][0], a);
      a = MFMA(ah[1], Bl[tl][1], a);
      g4[tl] = a;
    }
    #pragma unroll
    for (int tl = 0; tl < 4; tl++)
      *(float4_t*)&LPP[tl*PTL + cw*PSTR + q*4] = g4[tl];
    __syncthreads();   // barrier 1

    // ph2: lane-packed activations for 2 h-elems (rows 2q+e, col cw)
    float2_t pg[4];
    #pragma unroll
    for (int tl = 0; tl < 4; tl++)
      pg[tl] = *(const float2_t*)&LPP[tl*PTL + cw*PSTR + 2*q];
    #pragma unroll
    for (int e = 0; e < 2; e++){
      const float ig = frcp(1.f + fexp2(pg[0][e]));            // scales pre-folded
      const float fg = frcp(1.f + fexp2(pg[1][e]));
      const float gg = 1.f - 2.f*frcp(1.f + fexp2(pg[2][e]));
      const float og = frcp(1.f + fexp2(pg[3][e]));
      creg[e] = fg*creg[e] + ig*gg;
      const float th = 1.f - 2.f*frcp(1.f + fexp2(2.88539008f*creg[e]));
      const float h  = og * th;
      const unsigned u  = __float_as_uint(h);
      const float    lf = h - __uint_as_float(u & 0xFFFF0000u);  // exact trunc-split
      const int m = 2*q + e;
      HS[m*72 + cw]        = (unsigned short)(u >> 16);
      HS[1152 + m*72 + cw] = (unsigned short)(__float_as_uint(lf) >> 16);
    }

    // xg for t+1 (independent; reads packed x)
    { const int tn = t + 1;
      const int base = ((tn >> 6) & 1) * 2048 + (tn & (TCHUNK-1)) * 32;
      #pragma unroll
      for (int r = 0; r < 4; r++){
        const float4_t xv = *(const float4_t*)&XP4[base + (m4+r)*4];
        #pragma unroll
        for (int tl = 0; tl < 4; tl++)
          xg[tl][r] = __builtin_fmaf(xv[0], Wi0[tl],
                      __builtin_fmaf(xv[1], Wi1[tl],
                      __builtin_fmaf(xv[2], Wi2[tl], bia[tl])));
      }
    }
    __syncthreads();   // barrier 2
  }

  // epilogue: decode out(511), flush last chunk
  { const unsigned short* ph = &HS[lid*72 + q*8];
    ah[0] = *(const bf16x8*)&ph[0];  ah[1] = *(const bf16x8*)&ph[32];
    const unsigned short* pl = &HS[1152 + lid*72 + q*8];
    al[0] = *(const bf16x8*)&pl[0];  al[1] = *(const bf16x8*)&pl[32]; }
  if (w == 0){
    float4_t d = {bdec, bdec, bdec, bdec};
    d = MFMA(ah[0], Dh[0], d);
    d = MFMA(ah[1], Dh[1], d);
    d = MFMA(al[0], Dh[0], d);
    d = MFMA(al[1], Dh[1], d);
    d = MFMA(ah[0], Dl[0], d);
    d = MFMA(ah[1], Dl[1], d);
    if (lid < 3 && q < 2){
      #pragma unroll
      for (int r = 0; r < 4; r++) OOF[(q*4+r)*196 + 63*3 + lid] = d[r];
    }
  }
  __syncthreads();
  #pragma unroll
  for (int s = 0; s < 2; s++){
    const int f = tid + 256*s;
    if (f < 384){ const int row = f/48, off = (f%48)*4;
      *(float4_t*)(out + (size_t)(b0+row)*1536 + (NCHUNK-1)*192 + off)
          = *(const float4_t*)&OOF[row*196+off]; }
  }
}

extern "C" void kernel_launch(void* const* d_in, const int* in_sizes, int n_in,
                              void* d_out, int out_size, void* d_ws, size_t ws_size,
                              hipStream_t stream)
{
  const float* x     = (const float*)d_in[0];
  const float* W_ih  = (const float*)d_in[1];
  const float* W_hh  = (const float*)d_in[2];
  const float* b_ih  = (const float*)d_in[3];
  const float* b_hh  = (const float*)d_in[4];
  const float* W_dec = (const float*)d_in[5];
  const float* b_dec = (const float*)d_in[6];
  float* out = (float*)d_out;

  const int B = in_sizes[0] / (TLEN * 3);   // 4096
  const int blocks = B / 8;                 // 512 -> 2 blocks/CU
  hipLaunchKernelGGL(LSTMAnomalyDetector_kernel, dim3(blocks), dim3(256), 0, stream,
                     x, W_ih, W_hh, b_ih, b_hh, W_dec, b_dec, out);
}

// Round 6
// 542.007 us; speedup vs baseline: 1.0210x; 1.0210x over previous
//
#include <hip/hip_runtime.h>

// LSTM anomaly detector: B=4096, T=512, I=3, H=64 (4H=256 gates)
// R6: back to 16-row blocks (grid=256, 1/CU). The step is latency-chain
// bound, so this round shortens the serial chain:
//  - 3 parallel 2-deep MFMA chains per tile (was one 6-deep chain)
//  - activation scales folded into weights; c kept pre-scaled (cs=2.885c)
//  - branch-free inner loop: x-refill hoisted between chunks (parity LDS),
//    decode writes straight to global (no out staging, no extra barriers)
//  - decode = 4 MFMAs (bf16-hi W_dec), rotating wave, two 2-deep chains
//  - 1 barrier/step; h parity double-buffer; producer-split bf16 hi/lo h

#define TLEN 512

typedef float  float4_t __attribute__((ext_vector_type(4)));
typedef __bf16 bf16x8   __attribute__((ext_vector_type(8)));

__device__ __forceinline__ float fexp2(float x){ return __builtin_amdgcn_exp2f(x); }
__device__ __forceinline__ float frcp (float x){ return __builtin_amdgcn_rcpf(x); }

// setup-only: scale then RNE hi/lo split (~2^-17 rel err)
__device__ __forceinline__ void split8s(const float* v, float s, bf16x8& hi, bf16x8& lo){
  #pragma unroll
  for (int j = 0; j < 8; j++){
    const float xx = v[j]*s;
    __bf16 h = (__bf16)xx;
    hi[j] = h;
    lo[j] = (__bf16)(xx - (float)h);
  }
}

#define MFMA(a,b,c) __builtin_amdgcn_mfma_f32_16x16x32_bf16((a),(b),(c),0,0,0)

__global__ __launch_bounds__(256, 1)
void LSTMAnomalyDetector_kernel(
    const float* __restrict__ x,     const float* __restrict__ W_ih,
    const float* __restrict__ W_hh,  const float* __restrict__ b_ih,
    const float* __restrict__ b_hh,  const float* __restrict__ W_dec,
    const float* __restrict__ b_dec, float* __restrict__ out)
{
  __shared__ __align__(16) unsigned short HSH[2][1152];  // h hi, [16 m][72], parity
  __shared__ __align__(16) unsigned short HSL[2][1152];  // h lo
  __shared__ __align__(16) float XP[2*3136];             // x chunks, [16 row][196], parity

  const int tid  = threadIdx.x;
  const int w    = tid >> 6;        // wave 0..3 (owns H-cols w*16..w*16+15 of all gates)
  const int lane = tid & 63;
  const int q    = lane >> 4;
  const int lid  = lane & 15;
  const int b0   = blockIdx.x * 16;
  const int cw   = w*16 + lid;

  // ---- resident weights, activation scales folded in ----
  // i,f,o: sigmoid(v)=rcp(1+exp2(-1.4427 v)) -> scale -1.4427
  // g:     tanh(v)=1-2rcp(1+exp2(+2.8854 v)) -> scale +2.8854
  const float sc[4] = {-1.44269504f, -1.44269504f, 2.88539008f, -1.44269504f};
  bf16x8 Bh[4][2], Bl[4][2];
  bf16x8 Dh[2];
  float  Wi0[4], Wi1[4], Wi2[4], bia[4];

  #pragma unroll
  for (int tl = 0; tl < 4; tl++){
    const int g = tl*64 + cw;                 // gate row of W_hh[256][64]
    #pragma unroll
    for (int kt = 0; kt < 2; kt++){
      const float* p = W_hh + g*64 + kt*32 + q*8;
      float v[8];
      #pragma unroll
      for (int j = 0; j < 8; j++) v[j] = p[j];
      split8s(v, sc[tl], Bh[tl][kt], Bl[tl][kt]);
    }
    Wi0[tl] = W_ih[g*3+0]*sc[tl];
    Wi1[tl] = W_ih[g*3+1]*sc[tl];
    Wi2[tl] = W_ih[g*3+2]*sc[tl];
    bia[tl] = (b_ih[g] + b_hh[g])*sc[tl];
  }
  {
    bf16x8 dummy;
    #pragma unroll
    for (int kt = 0; kt < 2; kt++){
      float v[8] = {0.f,0.f,0.f,0.f,0.f,0.f,0.f,0.f};
      if (lid < 3){
        const float* p = W_dec + lid*64 + kt*32 + q*8;
        #pragma unroll
        for (int j = 0; j < 8; j++) v[j] = p[j];
      }
      split8s(v, 1.0f, Dh[kt], dummy);
    }
  }
  const float bdec = (lid < 3) ? b_dec[lid] : 0.f;

  // ---- zero h (both parities; h_{-1}=0) ----
  for (int i = tid; i < 1152; i += 256){
    ((unsigned int*)HSH)[i] = 0u;
    ((unsigned int*)HSL)[i] = 0u;
  }

  // ---- refill chunk 0 -> XP parity 0 ----
  #pragma unroll
  for (int s = 0; s < 3; s++){
    const int f = tid + 256*s; const int row = f/48, off = (f%48)*4;
    *(float4_t*)&XP[row*196 + off] =
        *(const float4_t*)(x + (size_t)(b0+row)*1536 + off);
  }
  __syncthreads();

  // ---- state ----
  float creg[4] = {0.f,0.f,0.f,0.f};   // cs = 2.8854*c for (row q*4+r, col cw)
  float4_t xg[4];
  #pragma unroll
  for (int r = 0; r < 4; r++){
    const float* xp = &XP[(q*4+r)*196];
    #pragma unroll
    for (int tl = 0; tl < 4; tl++)
      xg[tl][r] = __builtin_fmaf(xp[0], Wi0[tl],
                  __builtin_fmaf(xp[1], Wi1[tl],
                  __builtin_fmaf(xp[2], Wi2[tl], bia[tl])));
  }
  bf16x8 ah0, ah1, al0, al1;

  for (int c = 0; c < 8; ++c){
    // refill chunk c+1 into parity ~ (c&1); readers of it start at this
    // chunk's dt=63 xg-prefetch -> 63 barriers of separation, no sync needed
    if (c < 7){
      const int pp = (c+1) & 1;
      #pragma unroll
      for (int s = 0; s < 3; s++){
        const int f = tid + 256*s; const int row = f/48, off = (f%48)*4;
        *(float4_t*)&XP[pp*3136 + row*196 + off] =
            *(const float4_t*)(x + (size_t)(b0+row)*1536 + (c+1)*192 + off);
      }
    }
    const int tbase = c*64;
    #pragma unroll 2
    for (int dt = 0; dt < 64; ++dt){
      const int t  = tbase + dt;
      const int p  = t & 1, rp = p ^ 1;

      // A-frags of h_{t-1}: 4 raw ds_read_b128
      { const unsigned short* ph = &HSH[rp][lid*72 + q*8];
        ah0 = *(const bf16x8*)&ph[0]; ah1 = *(const bf16x8*)&ph[32];
        const unsigned short* pl = &HSL[rp][lid*72 + q*8];
        al0 = *(const bf16x8*)&pl[0]; al1 = *(const bf16x8*)&pl[32]; }

      // xg for t+1 (independent of the reads; covers LDS latency)
      float4_t nxg[4];
      { const int tn = t + 1;
        const int xb = ((tn >> 6) & 1)*3136 + (tn & 63)*3;
        #pragma unroll
        for (int r = 0; r < 4; r++){
          const float* xp = &XP[xb + (q*4+r)*196];
          const float x0 = xp[0], x1 = xp[1], x2 = xp[2];
          #pragma unroll
          for (int tl = 0; tl < 4; tl++)
            nxg[tl][r] = __builtin_fmaf(x0, Wi0[tl],
                         __builtin_fmaf(x1, Wi1[tl],
                         __builtin_fmaf(x2, Wi2[tl], bia[tl])));
        }
      }

      // decode out(t-1) on rotating wave; direct global stores (12B/row)
      if (t > 0 && w == (t & 3)){
        float4_t dA = {bdec, bdec, bdec, bdec};
        float4_t dB = {0.f, 0.f, 0.f, 0.f};
        dA = MFMA(ah0, Dh[0], dA); dA = MFMA(ah1, Dh[1], dA);
        dB = MFMA(al0, Dh[0], dB); dB = MFMA(al1, Dh[1], dB);
        const float4_t d = dA + dB;
        if (lid < 3){
          #pragma unroll
          for (int r = 0; r < 4; r++)
            out[(size_t)(b0 + q*4 + r)*1536 + (t-1)*3 + lid] = d[r];
        }
      }

      // gate preacts: 3 parallel 2-deep chains per tile
      float4_t g4[4];
      #pragma unroll
      for (int tl = 0; tl < 4; tl++){
        float4_t cA = xg[tl];
        float4_t cB = {0.f,0.f,0.f,0.f};
        float4_t cC = {0.f,0.f,0.f,0.f};
        cA = MFMA(ah0, Bh[tl][0], cA); cA = MFMA(ah1, Bh[tl][1], cA);
        cB = MFMA(al0, Bh[tl][0], cB); cB = MFMA(al1, Bh[tl][1], cB);
        cC = MFMA(ah0, Bl[tl][0], cC); cC = MFMA(ah1, Bl[tl][1], cC);
        g4[tl] = (cA + cB) + cC;
      }

      // lane-local activations (scales pre-folded; c kept as cs=2.8854c)
      #pragma unroll
      for (int r = 0; r < 4; r++){
        const float si = frcp(1.f + fexp2(g4[0][r]));
        const float sf = frcp(1.f + fexp2(g4[1][r]));
        const float rg = frcp(1.f + fexp2(g4[2][r]));
        const float so = frcp(1.f + fexp2(g4[3][r]));
        const float ggs = __builtin_fmaf(-5.77078016f, rg, 2.88539008f); // 2.8854*tanh
        const float cs  = __builtin_fmaf(sf, creg[r], si*ggs);
        creg[r] = cs;
        const float rc = frcp(1.f + fexp2(cs));     // th = 1-2*rc
        const float hm = so*rc;
        const float h  = __builtin_fmaf(-2.f, hm, so);
        const unsigned u  = __float_as_uint(h);
        const float    lf = h - __uint_as_float(u & 0xFFFF0000u);  // exact
        const int m = q*4 + r;
        HSH[p][m*72 + cw] = (unsigned short)(u >> 16);
        HSL[p][m*72 + cw] = (unsigned short)(__float_as_uint(lf) >> 16);
      }

      #pragma unroll
      for (int tl = 0; tl < 4; tl++) xg[tl] = nxg[tl];
      __syncthreads();   // the ONE barrier per step
    }
  }

  // final decode: out(511) from h_511 (parity 1), wave 0
  { const unsigned short* ph = &HSH[1][lid*72 + q*8];
    ah0 = *(const bf16x8*)&ph[0]; ah1 = *(const bf16x8*)&ph[32];
    const unsigned short* pl = &HSL[1][lid*72 + q*8];
    al0 = *(const bf16x8*)&pl[0]; al1 = *(const bf16x8*)&pl[32]; }
  if (w == 0){
    float4_t dA = {bdec, bdec, bdec, bdec};
    float4_t dB = {0.f, 0.f, 0.f, 0.f};
    dA = MFMA(ah0, Dh[0], dA); dA = MFMA(ah1, Dh[1], dA);
    dB = MFMA(al0, Dh[0], dB); dB = MFMA(al1, Dh[1], dB);
    const float4_t d = dA + dB;
    if (lid < 3){
      #pragma unroll
      for (int r = 0; r < 4; r++)
        out[(size_t)(b0 + q*4 + r)*1536 + 511*3 + lid] = d[r];
    }
  }
}

extern "C" void kernel_launch(void* const* d_in, const int* in_sizes, int n_in,
                              void* d_out, int out_size, void* d_ws, size_t ws_size,
                              hipStream_t stream)
{
  const float* x     = (const float*)d_in[0];
  const float* W_ih  = (const float*)d_in[1];
  const float* W_hh  = (const float*)d_in[2];
  const float* b_ih  = (const float*)d_in[3];
  const float* b_hh  = (const float*)d_in[4];
  const float* W_dec = (const float*)d_in[5];
  const float* b_dec = (const float*)d_in[6];
  float* out = (float*)d_out;

  const int B = in_sizes[0] / (TLEN * 3);   // 4096
  const int blocks = B / 16;                // 256
  hipLaunchKernelGGL(LSTMAnomalyDetector_kernel, dim3(blocks), dim3(256), 0, stream,
                     x, W_ih, W_hh, b_ih, b_hh, W_dec, b_dec, out);
}